// Round 4
// baseline (291.137 us; speedup 1.0000x reference)
//
#include <hip/hip_runtime.h>
#include <hip/hip_bf16.h>

#define NEG_SLOPE 0.2f
#define LN_EPS 1e-5f
#define SM_EPS 1e-16f

typedef __attribute__((ext_vector_type(8))) short bf16x8;
typedef __attribute__((ext_vector_type(4))) float f32x4;

__device__ inline unsigned short f2bf(float f) {
    unsigned u = __float_as_uint(f);
    return (unsigned short)((u + 0x7FFFu + ((u >> 16) & 1u)) >> 16);
}

// ---------------------------------------------------------------------------
// K1: fused bf16-MFMA GEMM + attention dots + bf16 pack. (unchanged, verified)
// ---------------------------------------------------------------------------
__global__ __launch_bounds__(256) void k_gemm(const float* __restrict__ X,
                                              const float* __restrict__ W,
                                              const float* __restrict__ att_src,
                                              const float* __restrict__ att_dst,
                                              unsigned int* __restrict__ xp,
                                              float2* __restrict__ aS,
                                              float2* __restrict__ aD, int N) {
    __shared__ unsigned short Ws[128 * 136];
    __shared__ unsigned short Xs[64 * 136];
    const int t = threadIdx.x;
    const int b0 = blockIdx.x * 64;
    const int lane = t & 63;
    const int w = t >> 6;
    const int c15 = lane & 15;
    const int quad = lane >> 4;

#pragma unroll
    for (int i = 0; i < 16; ++i) {
        int f = i * 256 + t;
        int nr = f >> 5;
        int q = f & 31;
        float4 v = reinterpret_cast<const float4*>(W)[nr * 32 + q];
        ushort4 b;
        b.x = f2bf(v.x); b.y = f2bf(v.y); b.z = f2bf(v.z); b.w = f2bf(v.w);
        *reinterpret_cast<ushort4*>(&Ws[nr * 136 + q * 4]) = b;
    }
#pragma unroll
    for (int i = 0; i < 8; ++i) {
        int f = i * 256 + t;
        int m = f >> 5;
        int q = f & 31;
        int gr = b0 + m;
        if (gr >= N) gr = N - 1;
        float4 v = reinterpret_cast<const float4*>(X)[(size_t)gr * 32 + q];
        ushort4 b;
        b.x = f2bf(v.x); b.y = f2bf(v.y); b.z = f2bf(v.z); b.w = f2bf(v.w);
        *reinterpret_cast<ushort4*>(&Xs[m * 136 + q * 4]) = b;
    }
    __syncthreads();

    f32x4 acc[8];
#pragma unroll
    for (int ct = 0; ct < 8; ++ct) acc[ct] = (f32x4){0.f, 0.f, 0.f, 0.f};

#pragma unroll
    for (int kc = 0; kc < 4; ++kc) {
        bf16x8 af = *reinterpret_cast<const bf16x8*>(
            &Xs[(w * 16 + c15) * 136 + kc * 32 + quad * 8]);
#pragma unroll
        for (int ct = 0; ct < 8; ++ct) {
            bf16x8 bfr = *reinterpret_cast<const bf16x8*>(
                &Ws[(ct * 16 + c15) * 136 + kc * 32 + quad * 8]);
            acc[ct] = __builtin_amdgcn_mfma_f32_16x16x32_bf16(af, bfr, acc[ct], 0, 0, 0);
        }
    }

    float attS[8], attD[8];
#pragma unroll
    for (int ct = 0; ct < 8; ++ct) {
        attS[ct] = att_src[ct * 16 + c15];
        attD[ct] = att_dst[ct * 16 + c15];
    }

#pragma unroll
    for (int r = 0; r < 4; ++r) {
        int row = b0 + w * 16 + quad * 4 + r;
        float s0 = 0.f, s1 = 0.f, d0 = 0.f, d1 = 0.f;
#pragma unroll
        for (int ct = 0; ct < 4; ++ct) {
            s0 += acc[ct][r] * attS[ct];
            d0 += acc[ct][r] * attD[ct];
            s1 += acc[ct + 4][r] * attS[ct + 4];
            d1 += acc[ct + 4][r] * attD[ct + 4];
        }
#pragma unroll
        for (int o = 1; o < 16; o <<= 1) {
            s0 += __shfl_xor(s0, o);
            s1 += __shfl_xor(s1, o);
            d0 += __shfl_xor(d0, o);
            d1 += __shfl_xor(d1, o);
        }
        if (row < N) {
#pragma unroll
            for (int ct = 0; ct < 4; ++ct) {
                unsigned int p = (unsigned int)f2bf(acc[ct][r]) |
                                 ((unsigned int)f2bf(acc[ct + 4][r]) << 16);
                xp[(size_t)row * 64 + ct * 16 + c15] = p;
            }
            if (c15 == 0) {
                aS[row] = make_float2(s0, s1);
                aD[row] = make_float2(d0, d1);
            }
        }
    }
}

// ---------------------------------------------------------------------------
// Atomic-free CSR build via 2-level counting sort on dst.
// ---------------------------------------------------------------------------
#define SORT_CHUNK 8192
#define NBIN 512

__global__ __launch_bounds__(256) void k_sort_count(const int* __restrict__ ei,
                                                    int* __restrict__ blockCnt,
                                                    int E, int NB) {
    __shared__ int hist[NBIN];
    const int t = threadIdx.x;
    for (int i = t; i < NBIN; i += 256) hist[i] = 0;
    __syncthreads();
    const int base = blockIdx.x * SORT_CHUNK;
#pragma unroll
    for (int k = 0; k < 32; ++k) {
        int i = base + k * 256 + t;
        if (i < E) atomicAdd(&hist[ei[E + i] >> 8], 1);
    }
    __syncthreads();
    for (int i = t; i < NBIN; i += 256)
        blockCnt[i * NB + blockIdx.x] = hist[i];
}

__global__ __launch_bounds__(256) void k_scan1(const int* __restrict__ data,
                                               int* __restrict__ blockSums, int M) {
    __shared__ int lds[4];
    const int t = threadIdx.x;
    int base = blockIdx.x * 1024 + t * 4;
    int s = 0;
    for (int c = 0; c < 4; ++c) {
        int i = base + c;
        if (i < M) s += data[i];
    }
    int lane = t & 63, w = t >> 6;
    for (int o = 32; o > 0; o >>= 1) s += __shfl_down(s, o);
    if (lane == 0) lds[w] = s;
    __syncthreads();
    if (t == 0) blockSums[blockIdx.x] = lds[0] + lds[1] + lds[2] + lds[3];
}

__global__ void k_scan2(int* __restrict__ blockSums, int nb) {
    __shared__ int buf[256];
    const int t = threadIdx.x;
    int v = (t < nb) ? blockSums[t] : 0;
    buf[t] = v;
    __syncthreads();
    for (int o = 1; o < 256; o <<= 1) {
        int u = (t >= o) ? buf[t - o] : 0;
        __syncthreads();
        buf[t] += u;
        __syncthreads();
    }
    if (t < nb) blockSums[t] = buf[t] - v;
}

__global__ __launch_bounds__(256) void k_scan3(int* __restrict__ data,
                                               const int* __restrict__ blockSums, int M) {
    __shared__ int lds[4];
    const int t = threadIdx.x;
    int base = blockIdx.x * 1024 + t * 4;
    int c[4];
    int s = 0;
#pragma unroll
    for (int i = 0; i < 4; ++i) {
        int idx = base + i;
        c[i] = (idx < M) ? data[idx] : 0;
        s += c[i];
    }
    int lane = t & 63, w = t >> 6;
    int incl = s;
#pragma unroll
    for (int o = 1; o < 64; o <<= 1) {
        int u = __shfl_up(incl, o);
        if (lane >= o) incl += u;
    }
    if (lane == 63) lds[w] = incl;
    __syncthreads();
    if (t == 0) {
        int run = 0;
        for (int i = 0; i < 4; ++i) { int tmp = lds[i]; lds[i] = run; run += tmp; }
    }
    __syncthreads();
    int off = blockSums[blockIdx.x] + lds[w] + incl - s;
#pragma unroll
    for (int i = 0; i < 4; ++i) {
        int idx = base + i;
        if (idx < M) { data[idx] = off; off += c[i]; }
    }
}

__global__ __launch_bounds__(256) void k_sort_scatter(const int* __restrict__ ei,
                                                      const int* __restrict__ scanned,
                                                      uint2* __restrict__ tmp,
                                                      int E, int NB) {
    __shared__ int off[NBIN];
    const int t = threadIdx.x;
    for (int i = t; i < NBIN; i += 256) off[i] = scanned[i * NB + blockIdx.x];
    __syncthreads();
    const int base = blockIdx.x * SORT_CHUNK;
#pragma unroll
    for (int k = 0; k < 32; ++k) {
        int i = base + k * 256 + t;
        if (i < E) {
            int s = ei[i];
            int d = ei[E + i];
            int p = atomicAdd(&off[d >> 8], 1);
            tmp[p] = make_uint2((unsigned)d, (unsigned)s);
        }
    }
}

// ---------------------------------------------------------------------------
// k_bucket: one block per 256-dst bucket. Computes per-edge exp weights
// (thread-per-edge), per-dst softmax denominators (LDS float atomics),
// self-loop weights, invD; emits row_ptr, alphaSelf, and CSR entries as
// uint4 {src, alpha0, alpha1, 0} with alpha pre-normalized.
// ---------------------------------------------------------------------------
__global__ __launch_bounds__(256) void k_bucket(const uint2* __restrict__ tmp,
                                                const int* __restrict__ scanned,
                                                const float2* __restrict__ aS,
                                                const float2* __restrict__ aD,
                                                uint4* __restrict__ csr,
                                                int* __restrict__ row_ptr,
                                                float2* __restrict__ alphaSelf,
                                                int E, int NB, int N) {
    __shared__ int cnt[256];
    __shared__ int cur[256];
    __shared__ float den0[256], den1[256];
    __shared__ float inv0[256], inv1[256];
    __shared__ int lds[4];
    const int t = threadIdx.x;
    const int b = blockIdx.x;
    const int start = scanned[b * NB];
    const int end = (b + 1 < NBIN) ? scanned[(b + 1) * NB] : E;
    const int m = end - start;

    cnt[t] = 0; den0[t] = 0.f; den1[t] = 0.f;
    __syncthreads();

    // P1: weights -> denominators + counts
    for (int k = t; k < m; k += 256) {
        uint2 e = tmp[start + k];
        float2 a = aS[e.y];
        float2 ad = aD[e.x];
        float f0 = a.x + ad.x; f0 = fmaxf(f0, NEG_SLOPE * f0);
        float f1 = a.y + ad.y; f1 = fmaxf(f1, NEG_SLOPE * f1);
        float u0 = __expf(f0), u1 = __expf(f1);
        int li = e.x & 255;
        atomicAdd(&cnt[li], 1);
        atomicAdd(&den0[li], u0);
        atomicAdd(&den1[li], u1);
    }
    __syncthreads();

    // block exclusive scan of cnt
    int v = cnt[t];
    int lane = t & 63, w = t >> 6;
    int incl = v;
#pragma unroll
    for (int o = 1; o < 64; o <<= 1) {
        int u = __shfl_up(incl, o);
        if (lane >= o) incl += u;
    }
    if (lane == 63) lds[w] = incl;
    __syncthreads();
    if (t == 0) {
        int run = 0;
        for (int i = 0; i < 4; ++i) { int tmpv = lds[i]; lds[i] = run; run += tmpv; }
    }
    __syncthreads();
    int excl = lds[w] + incl - v;
    cur[t] = start + excl;

    // self-loop weight + invD + alphaSelf + row_ptr
    int d = b * 256 + t;
    float iv0 = 0.f, iv1 = 0.f;
    if (d < N) {
        float2 a = aS[d];
        float2 ad = aD[d];
        float f0 = a.x + ad.x; f0 = fmaxf(f0, NEG_SLOPE * f0);
        float f1 = a.y + ad.y; f1 = fmaxf(f1, NEG_SLOPE * f1);
        float ws0 = __expf(f0), ws1 = __expf(f1);
        float D0 = den0[t] + ws0, D1 = den1[t] + ws1;
        iv0 = 1.f / (D0 + SM_EPS);
        iv1 = 1.f / (D1 + SM_EPS);
        alphaSelf[d] = make_float2(ws0 * iv0, ws1 * iv1);
        row_ptr[d] = start + excl;
    }
    inv0[t] = iv0; inv1[t] = iv1;
    if (b == 0 && t == 0) row_ptr[N] = E;
    __syncthreads();

    // P2: recompute weights (L2-hot), normalize, emit CSR entries
    for (int k = t; k < m; k += 256) {
        uint2 e = tmp[start + k];
        float2 a = aS[e.y];
        float2 ad = aD[e.x];
        float f0 = a.x + ad.x; f0 = fmaxf(f0, NEG_SLOPE * f0);
        float f1 = a.y + ad.y; f1 = fmaxf(f1, NEG_SLOPE * f1);
        float u0 = __expf(f0), u1 = __expf(f1);
        int li = e.x & 255;
        int p = atomicAdd(&cur[li], 1);
        csr[p] = make_uint4(e.y, __float_as_uint(u0 * inv0[li]),
                            __float_as_uint(u1 * inv1[li]), 0u);
    }
}

// ---------------------------------------------------------------------------
// K5: per-dst aggregation + head-mean + bias + LayerNorm.
// Per edge per lane: 16B broadcast CSR load + 256B gather + 2 FMA.
// ---------------------------------------------------------------------------
__device__ inline float bf_lo(unsigned int v) { return __uint_as_float(v << 16); }
__device__ inline float bf_hi(unsigned int v) { return __uint_as_float(v & 0xffff0000u); }

__global__ __launch_bounds__(256) void k_agg(const unsigned int* __restrict__ xp,
                                             const float2* __restrict__ alphaSelf,
                                             const int* __restrict__ row_ptr,
                                             const uint4* __restrict__ csr,
                                             const float* __restrict__ bias,
                                             const float* __restrict__ gamma,
                                             const float* __restrict__ beta,
                                             float* __restrict__ out, int N) {
    const int w = threadIdx.x >> 6, lane = threadIdx.x & 63;
    const int n = blockIdx.x * 4 + w;
    if (n >= N) return;

    float2 asf = alphaSelf[n];
    unsigned int vself = xp[(size_t)n * 64 + lane];
    float S0 = asf.x * bf_lo(vself);
    float S1 = asf.y * bf_hi(vself);

    const int jb = row_ptr[n], je = row_ptr[n + 1];
    int j = jb;
    for (; j + 3 < je; j += 4) {
        uint4 c0 = csr[j], c1 = csr[j + 1], c2 = csr[j + 2], c3 = csr[j + 3];
        unsigned int v0 = xp[(size_t)c0.x * 64 + lane];
        unsigned int v1 = xp[(size_t)c1.x * 64 + lane];
        unsigned int v2 = xp[(size_t)c2.x * 64 + lane];
        unsigned int v3 = xp[(size_t)c3.x * 64 + lane];
        S0 += __uint_as_float(c0.y) * bf_lo(v0) + __uint_as_float(c1.y) * bf_lo(v1)
            + __uint_as_float(c2.y) * bf_lo(v2) + __uint_as_float(c3.y) * bf_lo(v3);
        S1 += __uint_as_float(c0.z) * bf_hi(v0) + __uint_as_float(c1.z) * bf_hi(v1)
            + __uint_as_float(c2.z) * bf_hi(v2) + __uint_as_float(c3.z) * bf_hi(v3);
    }
    for (; j < je; ++j) {
        uint4 c = csr[j];
        unsigned int vv = xp[(size_t)c.x * 64 + lane];
        S0 += __uint_as_float(c.y) * bf_lo(vv);
        S1 += __uint_as_float(c.z) * bf_hi(vv);
    }

    float o = 0.5f * (S0 + S1) + bias[lane];

    float mu = o;
#pragma unroll
    for (int d = 32; d > 0; d >>= 1) mu += __shfl_xor(mu, d);
    mu *= (1.0f / 64.0f);
    float dv = o - mu;
    float var = dv * dv;
#pragma unroll
    for (int d = 32; d > 0; d >>= 1) var += __shfl_xor(var, d);
    var *= (1.0f / 64.0f);
    out[(size_t)n * 64 + lane] = dv * rsqrtf(var + LN_EPS) * gamma[lane] + beta[lane];
}

// ---------------------------------------------------------------------------
extern "C" void kernel_launch(void* const* d_in, const int* in_sizes, int n_in,
                              void* d_out, int out_size, void* d_ws, size_t ws_size,
                              hipStream_t stream) {
    const float* X        = (const float*)d_in[0];
    const int*   ei       = (const int*)d_in[1];
    const float* W        = (const float*)d_in[2];
    const float* att_src  = (const float*)d_in[3];
    const float* att_dst  = (const float*)d_in[4];
    const float* bias     = (const float*)d_in[5];
    const float* ln_gamma = (const float*)d_in[6];
    const float* ln_beta  = (const float*)d_in[7];
    float* out = (float*)d_out;

    const int N = in_sizes[0] / 128;
    const int E = in_sizes[1] / 2;
    const int NB = (E + SORT_CHUNK - 1) / SORT_CHUNK;
    const int NBUCK = (N + 255) / 256;
    const int M = NBIN * NB;

    char* ws = (char*)d_ws;
    size_t off = 0;
    auto alloc = [&](size_t bytes) {
        size_t o = off;
        off += (bytes + 255) & ~(size_t)255;
        return o;
    };
    unsigned int* xp   = (unsigned int*)(ws + alloc((size_t)N * 64 * 4));
    float2* aS         = (float2*)(ws + alloc((size_t)N * 8));
    float2* aD         = (float2*)(ws + alloc((size_t)N * 8));
    float2* alphaSelf  = (float2*)(ws + alloc((size_t)N * 8));
    int* row_ptr       = (int*)(ws + alloc((size_t)(N + 1) * 4));
    uint4* csr         = (uint4*)(ws + alloc((size_t)E * 16));
    uint2* tmp         = (uint2*)(ws + alloc((size_t)E * 8));
    int* blockCnt      = (int*)(ws + alloc((size_t)M * 4));
    int* blockSums     = (int*)(ws + alloc(256 * 4));

    k_gemm<<<(N + 63) / 64, 256, 0, stream>>>(X, W, att_src, att_dst, xp, aS, aD, N);

    k_sort_count<<<NB, 256, 0, stream>>>(ei, blockCnt, E, NB);
    const int nb = (M + 1023) / 1024;
    k_scan1<<<nb, 256, 0, stream>>>(blockCnt, blockSums, M);
    k_scan2<<<1, 256, 0, stream>>>(blockSums, nb);
    k_scan3<<<nb, 256, 0, stream>>>(blockCnt, blockSums, M);
    k_sort_scatter<<<NB, 256, 0, stream>>>(ei, blockCnt, tmp, E, NB);
    k_bucket<<<NBUCK, 256, 0, stream>>>(tmp, blockCnt, aS, aD, csr, row_ptr,
                                        alphaSelf, E, NB, N);

    k_agg<<<(N + 3) / 4, 256, 0, stream>>>(xp, alphaSelf, row_ptr, csr,
                                           bias, ln_gamma, ln_beta, out, N);
}